// Round 4
// baseline (518.684 us; speedup 1.0000x reference)
//
#include <hip/hip_runtime.h>
#include <math.h>

#define KDEG 64

struct ZTab {
    float z0r[KDEG], z0i[KDEG], z1r[KDEG], z1i[KDEG];
    float scale;
};

// One wave (64 lanes) per row, 4 rows per 256-thread block.
// R3 post-mortem: LDS-staged coefficient broadcast flipped decision bits
// twice (cause not identifiable from source) — reverted to the proven R1
// data path. This round's change vs R1: NO readfirstlane on `row`, so the
// compiler cannot prove the coefficient addresses uniform and emits VMEM
// global_load_dword (uniform address -> 1 tx, HW broadcast into VGPR)
// instead of batched s_loads that overflow the SGPR file and stall on
// lgkmcnt. All 130 loads use one base address + immediate offsets.
// Arithmetic is strict numpy-complex64 rounding order: discrete
// mul/sub/add, no contraction — output is a hard 0/1 compare; any rounding
// change flips bits. Values here are bit-identical to R1 (load path only).
__global__ __launch_bounds__(256) void decoder_kernel(
    const float* __restrict__ xr, const float* __restrict__ xi,
    float* __restrict__ out, ZTab zt)
{
    const int lane = (int)(threadIdx.x & 63u);
    const int row = ((int)blockIdx.x * (int)blockDim.x + (int)threadIdx.x) >> 6;
    // NOTE: intentionally NOT readfirstlane'd — keeps loads on the VMEM path.

    const float* __restrict__ rr = xr + (size_t)row * (KDEG + 1);
    const float* __restrict__ ri = xi + (size_t)row * (KDEG + 1);

    const float z0r = zt.z0r[lane], z0i = zt.z0i[lane];
    const float z1r = zt.z1r[lane], z1i = zt.z1i[lane];

    // init = x[:, 0] broadcast
    float a0r = rr[0], a0i = ri[0];
    float a1r = a0r,  a1i = a0i;

#pragma unroll
    for (int i = 1; i <= KDEG; ++i) {
        const float cr = rr[i];
        const float ci = ri[i];
        // res = res*z + c, numpy complex64 order: (ar*br - ai*bi, ar*bi + ai*br)
        float t0r = __fadd_rn(__fsub_rn(__fmul_rn(a0r, z0r), __fmul_rn(a0i, z0i)), cr);
        float t0i = __fadd_rn(__fadd_rn(__fmul_rn(a0r, z0i), __fmul_rn(a0i, z0r)), ci);
        float t1r = __fadd_rn(__fsub_rn(__fmul_rn(a1r, z1r), __fmul_rn(a1i, z1i)), cr);
        float t1i = __fadd_rn(__fadd_rn(__fmul_rn(a1r, z1i), __fmul_rn(a1i, z1r)), ci);
        a0r = t0r; a0i = t0i;
        a1r = t1r; a1i = t1i;
    }

    // |res| matching numpy/glibc: (float)sqrt((double)a*a + (double)b*b).
    // Bit-exact requirement — do not replace with squared compare or f32 sqrt.
    float h0 = (float)sqrt((double)a0r * (double)a0r + (double)a0i * (double)a0i);
    float h1 = (float)sqrt((double)a1r * (double)a1r + (double)a1i * (double)a1i);

    out[(size_t)row * KDEG + lane] = (__fmul_rn(zt.scale, h0) >= h1) ? 1.0f : 0.0f;
}

extern "C" void kernel_launch(void* const* d_in, const int* in_sizes, int n_in,
                              void* d_out, int out_size, void* d_ws, size_t ws_size,
                              hipStream_t stream)
{
    const float* xr = (const float*)d_in[0];
    const float* xi = (const float*)d_in[1];
    float* out = (float*)d_out;

    const int B = in_sizes[0] / (KDEG + 1);  // 262144

    // Host-side constant table, replicating numpy's float64 math exactly
    // (same glibc libm as the reference environment), then rounding to f32.
    ZTab zt;
    const double r = sqrt(1.0 + sin(M_PI / (double)KDEG));
    const double inv_r = 1.0 / r;
    for (int j = 0; j < KDEG; ++j) {
        double ang = (2.0 * M_PI) * (double)j / (double)KDEG;  // ((2π)*j)/K, numpy order
        double c = cos(ang), s = sin(ang);
        zt.z0r[j] = (float)(inv_r * c);
        zt.z0i[j] = (float)(inv_r * s);
        zt.z1r[j] = (float)(r * c);
        zt.z1i[j] = (float)(r * s);
    }
    zt.scale = (float)pow(r, (double)KDEG);

    const int rows_per_block = 4;
    const int grid = (B + rows_per_block - 1) / rows_per_block;
    decoder_kernel<<<grid, 256, 0, stream>>>(xr, xi, out, zt);
}

// Round 5
// 467.832 us; speedup vs baseline: 1.1087x; 1.1087x over previous
//
#include <hip/hip_runtime.h>
#include <math.h>

#define KDEG 64

struct ZTab {
    float z0r[KDEG], z0i[KDEG], z1r[KDEG], z1i[KDEG];
    float scale;
};

// === R5: revert to the proven R1 kernel (session best: 402 µs, absmax 0.0) ===
// One wave (64 lanes) per row. Lane j evaluates the polynomial at z0[j] and
// z1[j] via Horner in strict numpy-complex64 rounding order (no fma, no
// reassociation) — the output is a hard 0/1 compare, so any rounding change
// flips decision bits.
//
// Load-path history (keep the scalar path!):
//  - R1 (this): readfirstlane(row) -> coefficients via batched s_load
//    (SMEM pipe, broadcast through SGPRs). 402 µs, VALUBusy 90%.
//  - R2/R3: LDS-staged broadcast — flipped decision bits even with
//    __syncthreads(); cause never identified from source. DO NOT RETRY blind.
//  - R4: VMEM uniform-address broadcast (no readfirstlane) — correct but
//    450 µs: address materialization added ~17% VALU slots (VGPR 16->36).
// Ceiling: 16 locked f32 ops/iter × 64 iters ≈ 1024 VALU insts/lane + f64
// epilogue ≈ practical throttled-VALU roof ~385-395 µs; R1 sits at 402.
__global__ __launch_bounds__(256) void decoder_kernel(
    const float* __restrict__ xr, const float* __restrict__ xi,
    float* __restrict__ out, ZTab zt)
{
    const int lane = (int)(threadIdx.x & 63u);
    int row = ((int)blockIdx.x * (int)blockDim.x + (int)threadIdx.x) >> 6;
    // row is wave-uniform; scalarize so coefficient loads hit the SMEM pipe.
    row = __builtin_amdgcn_readfirstlane(row);

    const float* __restrict__ rr = xr + (size_t)row * (KDEG + 1);
    const float* __restrict__ ri = xi + (size_t)row * (KDEG + 1);

    const float z0r = zt.z0r[lane], z0i = zt.z0i[lane];
    const float z1r = zt.z1r[lane], z1i = zt.z1i[lane];

    // init = x[:, 0] broadcast
    float a0r = rr[0], a0i = ri[0];
    float a1r = a0r,  a1i = a0i;

#pragma unroll
    for (int i = 1; i <= KDEG; ++i) {
        const float cr = rr[i];
        const float ci = ri[i];
        // res = res*z + c, numpy complex64 op order: (ar*br - ai*bi), (ar*bi + ai*br)
        float t0r = __fadd_rn(__fsub_rn(__fmul_rn(a0r, z0r), __fmul_rn(a0i, z0i)), cr);
        float t0i = __fadd_rn(__fadd_rn(__fmul_rn(a0r, z0i), __fmul_rn(a0i, z0r)), ci);
        float t1r = __fadd_rn(__fsub_rn(__fmul_rn(a1r, z1r), __fmul_rn(a1i, z1i)), cr);
        float t1i = __fadd_rn(__fadd_rn(__fmul_rn(a1r, z1i), __fmul_rn(a1i, z1r)), ci);
        a0r = t0r; a0i = t0i;
        a1r = t1r; a1i = t1i;
    }

    // |res| matching numpy/glibc hypotf: (float)sqrt((double)a*a + (double)b*b)
    // (float->double squares exact; one double rounding on the sum; IEEE double
    //  sqrt; final round to float). Bit-exact requirement — do not replace.
    float h0 = (float)sqrt((double)a0r * (double)a0r + (double)a0i * (double)a0i);
    float h1 = (float)sqrt((double)a1r * (double)a1r + (double)a1i * (double)a1i);

    out[(size_t)row * KDEG + lane] = (__fmul_rn(zt.scale, h0) >= h1) ? 1.0f : 0.0f;
}

extern "C" void kernel_launch(void* const* d_in, const int* in_sizes, int n_in,
                              void* d_out, int out_size, void* d_ws, size_t ws_size,
                              hipStream_t stream)
{
    const float* xr = (const float*)d_in[0];
    const float* xi = (const float*)d_in[1];
    float* out = (float*)d_out;

    const int B = in_sizes[0] / (KDEG + 1);  // 262144

    // Host-side constant table, replicating numpy's float64 math exactly
    // (same glibc libm as the reference environment), then rounding to f32.
    ZTab zt;
    const double r = sqrt(1.0 + sin(M_PI / (double)KDEG));
    const double inv_r = 1.0 / r;
    for (int j = 0; j < KDEG; ++j) {
        double ang = (2.0 * M_PI) * (double)j / (double)KDEG;  // ((2π)*j)/K, numpy order
        double c = cos(ang), s = sin(ang);
        zt.z0r[j] = (float)(inv_r * c);
        zt.z0i[j] = (float)(inv_r * s);
        zt.z1r[j] = (float)(r * c);
        zt.z1i[j] = (float)(r * s);
    }
    zt.scale = (float)pow(r, (double)KDEG);

    // One wave per row, 4 rows per 256-thread block.
    const int rows_per_block = 4;
    const int grid = (B + rows_per_block - 1) / rows_per_block;
    decoder_kernel<<<grid, 256, 0, stream>>>(xr, xi, out, zt);
}